// Round 4
// baseline (254.978 us; speedup 1.0000x reference)
//
#include <hip/hip_runtime.h>

// SpriteAssembler via MFMA, operand-swapped, identity-folded:
//   ACC[64i][16px] = W'[64i][64k] x B[64k][16px]   (f16 in, f32 acc)
// W part:   W[i][j] = tanh(relu(d_j - d_i)),  B[j][px] = log2(1 - s[px][j])
// id part:  acc[it] += Id x log2(s)  -- one extra MFMA per 16-row i-tile.
// masks = exp2(ACC) row-normalized (+eps).
// R4: back to R0 grid (1024 x 256thr, 128 px/wave). 2-deep prefetch + tile
//     loop unrolled x2 with named register sets, so two tiles' independent
//     chains interleave (cover load latency + shfl/store tails). Plain stores.

typedef __attribute__((ext_vector_type(8))) _Float16 half8;
typedef __attribute__((ext_vector_type(4))) float floatx4;

#define EPSF 1e-6f

__device__ inline float fast_exp2(float x){ return __builtin_amdgcn_exp2f(x); }
__device__ inline float fast_log2(float x){ return __builtin_amdgcn_logf(x); }  // log2
__device__ inline float fast_rcp (float x){ return __builtin_amdgcn_rcpf(x); }

__global__ __launch_bounds__(256, 4) void sprite_mfma_kernel(
    const float* __restrict__ shapes,   // [8, 65536, 64]
    const float* __restrict__ depths,   // [8, 64]
    float* __restrict__ out)            // [8, 65536, 64]
{
    const int wave  = threadIdx.x >> 6;
    const int lane  = threadIdx.x & 63;
    const int batch = blockIdx.x >> 7;   // 128 blocks per batch
    const int rblk  = blockIdx.x & 127;
    const int wid   = rblk * 4 + wave;   // wave id within batch [0,512), 128 px each

    __shared__ float dsh[64];
    if (threadIdx.x < 64) dsh[threadIdx.x] = depths[batch * 64 + threadIdx.x];
    __syncthreads();

    const int c = lane & 15;   // A: m(i-local). B: n(px). D: col(px)
    const int q = lane >> 4;   // k-quad / D row group

    // ---- W fragments (A-operand), built once per wave, amortized over 128 px ----
    half8 Aw[4][2];
    #pragma unroll
    for (int it = 0; it < 4; ++it) {
        float di = dsh[it * 16 + c];
        #pragma unroll
        for (int kt = 0; kt < 2; ++kt) {
            half8 h;
            #pragma unroll
            for (int jj = 0; jj < 8; ++jj) {
                int j = kt * 32 + q * 8 + jj;
                float x = fmaxf(dsh[j] - di, 0.0f);            // relu(d_j - d_i)
                float e = fast_exp2(x * 2.885390082f);         // e^{2x}
                h[jj] = (_Float16)((e - 1.0f) * fast_rcp(e + 1.0f));  // tanh
            }
            Aw[it][kt] = h;
        }
    }

    // identity A-fragments: nonzero only where k_local == (it&1)*16 + m
    half8 idlo, idhi;
    #pragma unroll
    for (int jj = 0; jj < 8; ++jj) {
        idlo[jj] = (q * 8 + jj == c)      ? (_Float16)1.0f : (_Float16)0.0f;
        idhi[jj] = (q * 8 + jj == 16 + c) ? (_Float16)1.0f : (_Float16)0.0f;
    }

    const long pxbase = (long)batch * 65536 + (long)wid * 128;
    const float* sp = shapes + (pxbase + c) * 64 + q * 8;  // lane's row chunk, tile 0
    float* op = out + (pxbase + c) * 64;

    // ---- 2-deep prefetch: set A = tile t (even), set B = tile t+1 (odd) ----
    float4 pa0 = *(const float4*)(sp);
    float4 pa1 = *(const float4*)(sp + 4);
    float4 pa2 = *(const float4*)(sp + 32);
    float4 pa3 = *(const float4*)(sp + 36);
    const float* sp1 = sp + 16 * 64;
    float4 pb0 = *(const float4*)(sp1);
    float4 pb1 = *(const float4*)(sp1 + 4);
    float4 pb2 = *(const float4*)(sp1 + 32);
    float4 pb3 = *(const float4*)(sp1 + 36);

    auto body = [&](int tile, float4& p0, float4& p1, float4& p2, float4& p3) {
        float4 s0 = p0, s1 = p1, s2 = p2, s3 = p3;
        if (tile + 2 < 8) {                      // refill this set: tile+2
            const float* sn = sp + (tile + 2) * 16 * 64;
            p0 = *(const float4*)(sn);
            p1 = *(const float4*)(sn + 4);
            p2 = *(const float4*)(sn + 32);
            p3 = *(const float4*)(sn + 36);
        }

        float sv[16] = {s0.x, s0.y, s0.z, s0.w, s1.x, s1.y, s1.z, s1.w,
                        s2.x, s2.y, s2.z, s2.w, s3.x, s3.y, s3.z, s3.w};
        half8 B_lo, B_hi;                        // B[j][px=c]  = log2(1 - s)
        half8 C_lo, C_hi;                        // B2[j][px=c] = log2(s)
        #pragma unroll
        for (int e = 0; e < 8; ++e) {
            float slo = fminf(fmaxf(sv[e],     EPSF), 1.0f - EPSF);
            float shi = fminf(fmaxf(sv[8 + e], EPSF), 1.0f - EPSF);
            B_lo[e] = (_Float16)fast_log2(1.0f - slo);
            B_hi[e] = (_Float16)fast_log2(1.0f - shi);
            C_lo[e] = (_Float16)fast_log2(slo);
            C_hi[e] = (_Float16)fast_log2(shi);
        }

        floatx4 acc[4];
        #pragma unroll
        for (int it = 0; it < 4; ++it) {
            floatx4 a = {0.f, 0.f, 0.f, 0.f};
            a = __builtin_amdgcn_mfma_f32_16x16x32_f16(Aw[it][0], B_lo, a, 0, 0, 0);
            a = __builtin_amdgcn_mfma_f32_16x16x32_f16(Aw[it][1], B_hi, a, 0, 0, 0);
            a = __builtin_amdgcn_mfma_f32_16x16x32_f16(
                    (it & 1) ? idhi : idlo, (it < 2) ? C_lo : C_hi, a, 0, 0, 0);
            acc[it] = a;
        }

        // D layout: value (it, r) is ACC[i = it*16 + q*4 + r][px = tile*16 + c]
        float u[4][4];
        float tot = 0.f;
        #pragma unroll
        for (int it = 0; it < 4; ++it) {
            #pragma unroll
            for (int r = 0; r < 4; ++r) {
                float v = fast_exp2(acc[it][r]);
                u[it][r] = v;
                tot += v;
            }
        }
        tot += __shfl_xor(tot, 16, 64);          // reduce over q-groups (all 64 i)
        tot += __shfl_xor(tot, 32, 64);
        float inv = fast_rcp(tot + EPSF);

        float* orow = op + tile * 16 * 64;
        #pragma unroll
        for (int it = 0; it < 4; ++it) {
            floatx4 o = {u[it][0] * inv, u[it][1] * inv,
                         u[it][2] * inv, u[it][3] * inv};
            *(floatx4*)(orow + it * 16 + q * 4) = o;
        }
    };

    #pragma unroll
    for (int tp = 0; tp < 4; ++tp) {             // 8 tiles, unrolled in pairs
        body(2 * tp,     pa0, pa1, pa2, pa3);
        body(2 * tp + 1, pb0, pb1, pb2, pb3);
    }
}

extern "C" void kernel_launch(void* const* d_in, const int* in_sizes, int n_in,
                              void* d_out, int out_size, void* d_ws, size_t ws_size,
                              hipStream_t stream) {
    const float* shapes = (const float*)d_in[0];
    const float* depths = (const float*)d_in[1];
    float* out = (float*)d_out;
    // 8 batches * 128 blocks, 256 threads (4 waves), 128 px per wave
    sprite_mfma_kernel<<<1024, 256, 0, stream>>>(shapes, depths, out);
}

// Round 5
// 234.864 us; speedup vs baseline: 1.0856x; 1.0856x over previous
//
#include <hip/hip_runtime.h>

// SpriteAssembler via MFMA, operand-swapped, identity-folded, async-staged:
//   ACC[64i][16px] = W'[64i][64k] x B[64k][16px]   (f16 in, f32 acc)
// W part:   W[i][j] = tanh(relu(d_j - d_i)),  B[j][px] = log2(1 - s[px][j])
// id part:  acc[it] += Id x log2(s)  -- one extra MFMA per 16-row i-tile.
// masks = exp2(ACC) row-normalized (+eps).
// R5: global_load_lds (width 16) into a per-wave 3-slot LDS ring staged 2
//     tiles ahead, counted vmcnt (never 0 in loop), XOR-swizzled both sides
//     (linear LDS dest + pre-swizzled global src + swizzled ds_read) so
//     ds_read_b128 is bank-conflict-free. No barriers in the loop.

typedef __attribute__((ext_vector_type(8))) _Float16 half8;
typedef __attribute__((ext_vector_type(4))) float floatx4;

#define EPSF 1e-6f

__device__ inline float fast_exp2(float x){ return __builtin_amdgcn_exp2f(x); }
__device__ inline float fast_log2(float x){ return __builtin_amdgcn_logf(x); }  // log2
__device__ inline float fast_rcp (float x){ return __builtin_amdgcn_rcpf(x); }

#define WAITVM(N) asm volatile("s_waitcnt vmcnt(" #N ")" ::: "memory")
#define VMFENCE() asm volatile("" ::: "memory")

__global__ __launch_bounds__(256, 3) void sprite_mfma_kernel(
    const float* __restrict__ shapes,   // [8, 65536, 64]
    const float* __restrict__ depths,   // [8, 64]
    float* __restrict__ out)            // [8, 65536, 64]
{
    const int wave  = threadIdx.x >> 6;
    const int lane  = threadIdx.x & 63;
    const int batch = blockIdx.x >> 7;   // 128 blocks per batch
    const int rblk  = blockIdx.x & 127;
    const int wid   = rblk * 4 + wave;   // wave id within batch [0,512), 128 px each

    __shared__ float dsh[64];
    __shared__ __align__(16) char stage_lds[4][3][4096];  // [wave][slot][16px tile]

    if (threadIdx.x < 64) dsh[threadIdx.x] = depths[batch * 64 + threadIdx.x];
    __syncthreads();

    const int c = lane & 15;   // A: m(i-local). B: n(px). D: col(px)
    const int q = lane >> 4;   // k-quad / D row group

    // Per-lane pre-swizzled GLOBAL source offsets for the 4 DMA ops per tile.
    // LDS stays lane-linear (DMA writes base + lane*16); LDS[row][col] holds
    // global[row][col ^ s(row)], s(row) = ((row&7)<<5) ^ ((row&8)<<1).
    int gsw[4];
    #pragma unroll
    for (int k = 0; k < 4; ++k) {
        int row = k * 4 + (lane >> 4);
        int sw  = ((row & 7) << 5) ^ ((row & 8) << 1);
        gsw[k]  = row * 256 + (((lane & 15) * 16) ^ sw);
    }
    // Swizzled LDS read offsets (bytes within a tile) for this lane:
    // want global row c, bytes {q*32, q*32+16, 128+q*32, 144+q*32}.
    const int rsw = ((c & 7) << 5) ^ ((c & 8) << 1);
    const int a0 = c * 256 + (((q * 32)      ) ^ rsw);
    const int a1 = c * 256 + (((q * 32) +  16) ^ rsw);
    const int a2 = c * 256 + (((q * 32) + 128) ^ rsw);
    const int a3 = c * 256 + (((q * 32) + 144) ^ rsw);

    const long pxbase = (long)batch * 65536 + (long)wid * 128;
    const char* gwave = (const char*)(shapes + pxbase * 64);  // wave's 32KB
    float* op = out + (pxbase + c) * 64;

#define STAGE(T, SLOT) do {                                                   \
    const char* _g = gwave + (T) * 4096;                                      \
    char* _l = stage_lds[wave][(SLOT)];                                       \
    _Pragma("unroll")                                                         \
    for (int _k = 0; _k < 4; ++_k)                                            \
        __builtin_amdgcn_global_load_lds(                                     \
            (const __attribute__((address_space(1))) void*)(_g + gsw[_k]),    \
            (__attribute__((address_space(3))) void*)(_l + _k * 1024),        \
            16, 0, 0);                                                        \
} while (0)

    STAGE(0, 0);
    STAGE(1, 1);

    // ---- W fragments (A-operand), built under the first stages' flight ----
    half8 Aw[4][2];
    #pragma unroll
    for (int it = 0; it < 4; ++it) {
        float di = dsh[it * 16 + c];
        #pragma unroll
        for (int kt = 0; kt < 2; ++kt) {
            half8 h;
            #pragma unroll
            for (int jj = 0; jj < 8; ++jj) {
                int j = kt * 32 + q * 8 + jj;
                float x = fmaxf(dsh[j] - di, 0.0f);            // relu(d_j - d_i)
                float e = fast_exp2(x * 2.885390082f);         // e^{2x}
                h[jj] = (_Float16)((e - 1.0f) * fast_rcp(e + 1.0f));  // tanh
            }
            Aw[it][kt] = h;
        }
    }
    // identity A-fragments: nonzero only where k_local == (it&1)*16 + m
    half8 idlo, idhi;
    #pragma unroll
    for (int jj = 0; jj < 8; ++jj) {
        idlo[jj] = (q * 8 + jj == c)      ? (_Float16)1.0f : (_Float16)0.0f;
        idhi[jj] = (q * 8 + jj == 16 + c) ? (_Float16)1.0f : (_Float16)0.0f;
    }

    auto process = [&](float4 s0, float4 s1, float4 s2, float4 s3, int tile) {
        float sv[16] = {s0.x, s0.y, s0.z, s0.w, s1.x, s1.y, s1.z, s1.w,
                        s2.x, s2.y, s2.z, s2.w, s3.x, s3.y, s3.z, s3.w};
        half8 B_lo, B_hi;                        // B[j][px=c]  = log2(1 - s)
        half8 C_lo, C_hi;                        // B2[j][px=c] = log2(s)
        #pragma unroll
        for (int e = 0; e < 8; ++e) {
            float slo = fminf(fmaxf(sv[e],     EPSF), 1.0f - EPSF);
            float shi = fminf(fmaxf(sv[8 + e], EPSF), 1.0f - EPSF);
            B_lo[e] = (_Float16)fast_log2(1.0f - slo);
            B_hi[e] = (_Float16)fast_log2(1.0f - shi);
            C_lo[e] = (_Float16)fast_log2(slo);
            C_hi[e] = (_Float16)fast_log2(shi);
        }

        floatx4 acc[4];
        #pragma unroll
        for (int it = 0; it < 4; ++it) {
            floatx4 a = {0.f, 0.f, 0.f, 0.f};
            a = __builtin_amdgcn_mfma_f32_16x16x32_f16(Aw[it][0], B_lo, a, 0, 0, 0);
            a = __builtin_amdgcn_mfma_f32_16x16x32_f16(Aw[it][1], B_hi, a, 0, 0, 0);
            a = __builtin_amdgcn_mfma_f32_16x16x32_f16(
                    (it & 1) ? idhi : idlo, (it < 2) ? C_lo : C_hi, a, 0, 0, 0);
            acc[it] = a;
        }

        // D layout: value (it, r) is ACC[i = it*16 + q*4 + r][px = tile*16 + c]
        float u[4][4];
        float tot = 0.f;
        #pragma unroll
        for (int it = 0; it < 4; ++it) {
            #pragma unroll
            for (int r = 0; r < 4; ++r) {
                float v = fast_exp2(acc[it][r]);
                u[it][r] = v;
                tot += v;
            }
        }
        tot += __shfl_xor(tot, 16, 64);          // reduce over q-groups (all 64 i)
        tot += __shfl_xor(tot, 32, 64);
        float inv = fast_rcp(tot + EPSF);

        float* orow = op + tile * 16 * 64;
        #pragma unroll
        for (int it = 0; it < 4; ++it) {
            floatx4 o = {u[it][0] * inv, u[it][1] * inv,
                         u[it][2] * inv, u[it][3] * inv};
            *(floatx4*)(orow + it * 16 + q * 4) = o;
        }
    };

    // Per-tile: wait for this slot's DMA (counted; never 0), ds_read it,
    // issue next stage, then compute+store. vmcnt N = vmem ops issued after
    // this tile's stage: stages are 4 ops, store groups are 4 ops.
#define TILE(T, SLOT, NW, DOSTAGE, NSLOT) do {                                \
    WAITVM(NW);                                                               \
    __builtin_amdgcn_sched_barrier(0);                                        \
    const char* tb = stage_lds[wave][(SLOT)];                                 \
    float4 v0 = *(const float4*)(tb + a0);                                    \
    float4 v1 = *(const float4*)(tb + a1);                                    \
    float4 v2 = *(const float4*)(tb + a2);                                    \
    float4 v3 = *(const float4*)(tb + a3);                                    \
    if (DOSTAGE) STAGE((T) + 2, NSLOT);                                       \
    VMFENCE();                                                                \
    process(v0, v1, v2, v3, (T));                                             \
} while (0)

    TILE(0, 0,  4, 1, 2);
    TILE(1, 1,  8, 1, 0);
    TILE(2, 2, 12, 1, 1);
    TILE(3, 0, 12, 1, 2);
    TILE(4, 1, 12, 1, 0);
    TILE(5, 2, 12, 1, 1);
    TILE(6, 0, 12, 0, 0);
    TILE(7, 1,  8, 0, 0);

#undef TILE
#undef STAGE
}

extern "C" void kernel_launch(void* const* d_in, const int* in_sizes, int n_in,
                              void* d_out, int out_size, void* d_ws, size_t ws_size,
                              hipStream_t stream) {
    const float* shapes = (const float*)d_in[0];
    const float* depths = (const float*)d_in[1];
    float* out = (float*)d_out;
    // 8 batches * 128 blocks, 256 threads (4 waves), 128 px per wave
    sprite_mfma_kernel<<<1024, 256, 0, stream>>>(shapes, depths, out);
}

// Round 6
// 234.494 us; speedup vs baseline: 1.0874x; 1.0016x over previous
//
#include <hip/hip_runtime.h>

// SpriteAssembler via MFMA, operand-swapped, identity-folded:
//   ACC[64i][16px] = W'[64i][64k] x B[64k][16px]   (f16 in, f32 acc)
// W part:   W[i][j] = tanh(relu(d_j - d_i)),  B[j][px] = log2(1 - s[px][j])
// id part:  acc[it] += Id x log2(s)  -- one extra MFMA per 16-row i-tile.
// masks = exp2(ACC) row-normalized (+eps).
// R6: R2 structure (1024x256, reg loads, 1-deep prefetch) + LDS-transposed
//     store epilogue: u-tile staged in per-wave padded LDS, read back in
//     store-linear order -> 4 fully lane-contiguous 1KB stores per tile
//     (lane L -> base + 16*L). Targets the universal ~1.5 TB/s write rate.

typedef __attribute__((ext_vector_type(8))) _Float16 half8;
typedef __attribute__((ext_vector_type(4))) float floatx4;

#define EPSF 1e-6f

__device__ inline float fast_exp2(float x){ return __builtin_amdgcn_exp2f(x); }
__device__ inline float fast_log2(float x){ return __builtin_amdgcn_logf(x); }  // log2
__device__ inline float fast_rcp (float x){ return __builtin_amdgcn_rcpf(x); }

__global__ __launch_bounds__(256, 2) void sprite_mfma_kernel(
    const float* __restrict__ shapes,   // [8, 65536, 64]
    const float* __restrict__ depths,   // [8, 64]
    float* __restrict__ out)            // [8, 65536, 64]
{
    const int wave  = threadIdx.x >> 6;
    const int lane  = threadIdx.x & 63;
    const int batch = blockIdx.x >> 7;   // 128 blocks per batch
    const int rblk  = blockIdx.x & 127;
    const int wid   = rblk * 4 + wave;   // wave id within batch [0,512), 128 px each

    __shared__ float dsh[64];
    __shared__ __align__(16) float ustage[4][16][68];  // per-wave u-tile, +4 pad

    if (threadIdx.x < 64) dsh[threadIdx.x] = depths[batch * 64 + threadIdx.x];
    __syncthreads();

    const int c = lane & 15;   // A: m(i-local). B: n(px). D: col(px)
    const int q = lane >> 4;   // k-quad / D row group

    // ---- W fragments (A-operand), built once per wave, amortized over 128 px ----
    half8 Aw[4][2];
    #pragma unroll
    for (int it = 0; it < 4; ++it) {
        float di = dsh[it * 16 + c];
        #pragma unroll
        for (int kt = 0; kt < 2; ++kt) {
            half8 h;
            #pragma unroll
            for (int jj = 0; jj < 8; ++jj) {
                int j = kt * 32 + q * 8 + jj;
                float x = fmaxf(dsh[j] - di, 0.0f);            // relu(d_j - d_i)
                float e = fast_exp2(x * 2.885390082f);         // e^{2x}
                h[jj] = (_Float16)((e - 1.0f) * fast_rcp(e + 1.0f));  // tanh
            }
            Aw[it][kt] = h;
        }
    }

    // identity A-fragments: nonzero only where k_local == (it&1)*16 + m
    half8 idlo, idhi;
    #pragma unroll
    for (int jj = 0; jj < 8; ++jj) {
        idlo[jj] = (q * 8 + jj == c)      ? (_Float16)1.0f : (_Float16)0.0f;
        idhi[jj] = (q * 8 + jj == 16 + c) ? (_Float16)1.0f : (_Float16)0.0f;
    }

    const long pxbase = (long)batch * 65536 + (long)wid * 128;
    const float* sp = shapes + (pxbase + c) * 64 + q * 8;  // lane's row chunk, tile 0
    float* const obase0 = out + pxbase * 64;               // wave's contiguous 32KB

    // B-layout loads: lane reads s[px=c][q*8 .. q*8+7] and the +32 block.
    float4 pf0 = *(const float4*)(sp);
    float4 pf1 = *(const float4*)(sp + 4);
    float4 pf2 = *(const float4*)(sp + 32);
    float4 pf3 = *(const float4*)(sp + 36);

    for (int tile = 0; tile < 8; ++tile) {
        float4 s0 = pf0, s1 = pf1, s2 = pf2, s3 = pf3;
        if (tile < 7) {                          // software prefetch next tile
            const float* sn = sp + (tile + 1) * 16 * 64;
            pf0 = *(const float4*)(sn);
            pf1 = *(const float4*)(sn + 4);
            pf2 = *(const float4*)(sn + 32);
            pf3 = *(const float4*)(sn + 36);
        }

        float sv[16] = {s0.x, s0.y, s0.z, s0.w, s1.x, s1.y, s1.z, s1.w,
                        s2.x, s2.y, s2.z, s2.w, s3.x, s3.y, s3.z, s3.w};
        half8 B_lo, B_hi;                        // B[j][px=c]  = log2(1 - s)
        half8 C_lo, C_hi;                        // B2[j][px=c] = log2(s)
        #pragma unroll
        for (int e = 0; e < 8; ++e) {
            float slo = fminf(fmaxf(sv[e],     EPSF), 1.0f - EPSF);
            float shi = fminf(fmaxf(sv[8 + e], EPSF), 1.0f - EPSF);
            B_lo[e] = (_Float16)fast_log2(1.0f - slo);
            B_hi[e] = (_Float16)fast_log2(1.0f - shi);
            C_lo[e] = (_Float16)fast_log2(slo);
            C_hi[e] = (_Float16)fast_log2(shi);
        }

        floatx4 acc[4];
        #pragma unroll
        for (int it = 0; it < 4; ++it) {
            floatx4 a = {0.f, 0.f, 0.f, 0.f};
            a = __builtin_amdgcn_mfma_f32_16x16x32_f16(Aw[it][0], B_lo, a, 0, 0, 0);
            a = __builtin_amdgcn_mfma_f32_16x16x32_f16(Aw[it][1], B_hi, a, 0, 0, 0);
            a = __builtin_amdgcn_mfma_f32_16x16x32_f16(
                    (it & 1) ? idhi : idlo, (it < 2) ? C_lo : C_hi, a, 0, 0, 0);
            acc[it] = a;
        }

        // D layout: value (it, r) is ACC[i = it*16 + q*4 + r][px = tile*16 + c]
        float u[4][4];
        float tot = 0.f;
        #pragma unroll
        for (int it = 0; it < 4; ++it) {
            #pragma unroll
            for (int r = 0; r < 4; ++r) {
                float v = fast_exp2(acc[it][r]);
                u[it][r] = v;
                tot += v;
            }
        }
        tot += __shfl_xor(tot, 16, 64);          // reduce over q-groups (all 64 i)
        tot += __shfl_xor(tot, 32, 64);
        float inv = fast_rcp(tot + EPSF);

        // ---- LDS transpose epilogue (per-wave private; no barriers) ----
        // write D-layout: row px=c, i-cols it*16+q*4 .. +4
        #pragma unroll
        for (int it = 0; it < 4; ++it) {
            floatx4 o = {u[it][0] * inv, u[it][1] * inv,
                         u[it][2] * inv, u[it][3] * inv};
            *(floatx4*)&ustage[wave][c][it * 16 + q * 4] = o;
        }
        // read store-linear: instr k covers global bytes [k*1024 + lane*16)
        // px = k*4 + q, i-cols c*4 .. +4. Tile output is contiguous 4KB.
        float* ob = obase0 + (long)tile * 16 * 64;
        #pragma unroll
        for (int k = 0; k < 4; ++k) {
            floatx4 o = *(const floatx4*)&ustage[wave][k * 4 + q][c * 4];
            *(floatx4*)(ob + k * 256 + lane * 4) = o;
        }
    }
}

extern "C" void kernel_launch(void* const* d_in, const int* in_sizes, int n_in,
                              void* d_out, int out_size, void* d_ws, size_t ws_size,
                              hipStream_t stream) {
    const float* shapes = (const float*)d_in[0];
    const float* depths = (const float*)d_in[1];
    float* out = (float*)d_out;
    // 8 batches * 128 blocks, 256 threads (4 waves), 128 px per wave
    sprite_mfma_kernel<<<1024, 256, 0, stream>>>(shapes, depths, out);
}